// Round 2
// baseline (1574.839 us; speedup 1.0000x reference)
//
#include <hip/hip_runtime.h>
#include <hip/hip_bf16.h>

#define Bb 8
#define Tt 2048
#define Dd 512
#define Ss 4
#define GHh 64
#define NCHUNK 32
#define CLEN 64

typedef __hip_bfloat16 bf16;
__device__ __forceinline__ float b2f(bf16 x){ return __bfloat162float(x); }

// ---------------- K1: fused GEMM  M=B*T=16384, K=512, N=4352 ----------------
// N sections: [0,2048) pred -> err^2 partials (atomic)
//             [2048,4096) write-enc -> wenc (bf16)
//             [4096,4352) gate h-contrib -> hg (f32)
__global__ __launch_bounds__(256) void k1_gemm(
    const float* __restrict__ h, const float* __restrict__ predW, const float* __restrict__ predb,
    const float* __restrict__ gateW1, const float* __restrict__ writeW, const float* __restrict__ writeb,
    bf16* __restrict__ wenc, float* __restrict__ hg, float* __restrict__ errsq)
{
  __shared__ float As[16][68];
  __shared__ float Bs[16][68];
  __shared__ float red[64][17];
  const int tid = threadIdx.x;
  const int tileN = blockIdx.x;   // 0..67
  const int tileM = blockIdx.y;   // 0..255
  const int row0 = tileM * 64;
  const int n0 = tileN * 64;
  int sec = (n0 < 2048) ? 0 : (n0 < 4096 ? 1 : 2);

  float acc[4][4] = {};
  const int ty = tid >> 4, tx = tid & 15;

  for (int k0 = 0; k0 < 512; k0 += 16) {
    #pragma unroll
    for (int l = 0; l < 4; ++l) {
      int idx = l*256 + tid;
      int rm = idx >> 4, kk = idx & 15;
      As[kk][rm] = h[(size_t)(row0+rm)*512 + k0 + kk];
    }
    #pragma unroll
    for (int l = 0; l < 4; ++l) {
      int idx = l*256 + tid;
      int kk = idx >> 6, nl = idx & 63;
      int n = n0 + nl;
      int k = k0 + kk;
      float v;
      if (sec == 0) {
        int s = n >> 9, o = n & 511;
        v = predW[((size_t)s*512 + k)*512 + o];
      } else if (sec == 1) {
        int n2 = n - 2048; int s = n2 >> 9, o = n2 & 511;
        v = writeW[((size_t)s*512 + k)*512 + o];
      } else {
        int n2 = n - 4096; int s = n2 >> 6, hh = n2 & 63;
        v = gateW1[((size_t)s*521 + k)*64 + hh];
      }
      Bs[kk][nl] = v;
    }
    __syncthreads();
    #pragma unroll
    for (int kk = 0; kk < 16; ++kk) {
      float4 avv = *reinterpret_cast<const float4*>(&As[kk][ty*4]);
      float4 bvv = *reinterpret_cast<const float4*>(&Bs[kk][tx*4]);
      float a_[4] = {avv.x,avv.y,avv.z,avv.w};
      float b_[4] = {bvv.x,bvv.y,bvv.z,bvv.w};
      #pragma unroll
      for (int i=0;i<4;++i)
        #pragma unroll
        for (int j=0;j<4;++j)
          acc[i][j] = fmaf(a_[i], b_[j], acc[i][j]);
    }
    __syncthreads();
  }

  if (sec == 0) {
    int s = n0 >> 9;
    #pragma unroll
    for (int i=0;i<4;++i) {
      int r = row0 + ty*4 + i;
      int t = r & 2047;
      float sum = 0.f;
      if (t != 2047) {
        #pragma unroll
        for (int j=0;j<4;++j) {
          int o = (n0 & 511) + tx*4 + j;
          float P = acc[i][j] + predb[s*512 + o];
          float d = P - h[(size_t)(r+1)*512 + o];
          sum = fmaf(d, d, sum);
        }
      }
      red[ty*4+i][tx] = sum;
    }
    __syncthreads();
    if (tid < 64) {
      int r = row0 + tid;
      int t = r & 2047;
      float sum = 0.f;
      #pragma unroll
      for (int x=0;x<16;++x) sum += red[tid][x];
      if (t != 2047) atomicAdd(&errsq[(size_t)(r+1)*4 + s], sum);
    }
  } else if (sec == 1) {
    #pragma unroll
    for (int i=0;i<4;++i) {
      int r = row0 + ty*4 + i;
      #pragma unroll
      for (int j=0;j<4;++j) {
        int n2 = n0 - 2048 + tx*4 + j;
        int s = n2 >> 9, o = n2 & 511;
        float v = acc[i][j] + writeb[s*512 + o];
        wenc[((size_t)r*4 + s)*512 + o] = __float2bfloat16(v);
      }
    }
  } else {
    #pragma unroll
    for (int i=0;i<4;++i) {
      int r = row0 + ty*4 + i;
      #pragma unroll
      for (int j=0;j<4;++j) {
        int n2 = n0 - 4096 + tx*4 + j;
        int s = n2 >> 6, hh = n2 & 63;
        hg[((size_t)r*4 + s)*64 + hh] = acc[i][j];
      }
    }
  }
}

// ---------------- K2a: err = sqrt(errsq + 1e-8), 0 at t==0 ----------------
__global__ void k2a_err(const float* __restrict__ errsq, float* __restrict__ err){
  int i = blockIdx.x*256 + threadIdx.x;       // (b*T+t)*4+s
  int t = (i >> 2) & 2047;
  err[i] = (t > 0) ? sqrtf(errsq[i] + 1e-8f) : 0.f;
}

// ---------------- K2b: em[t,s] = mean_b err ----------------
__global__ void k2b_em(const float* __restrict__ err, float* __restrict__ em){
  int i = blockIdx.x*256 + threadIdx.x;       // t*4+s
  float sum = 0.f;
  #pragma unroll
  for (int b=0;b<8;++b) sum += err[b*8192 + i];
  em[i] = sum * 0.125f;
}

// ---------------- K2c: scalar EMA scan (mu or sigma) ----------------
__global__ void k2c_scan(const float* __restrict__ in, float* __restrict__ outv, float init){
  __shared__ float s_in[8192];
  for (int i = threadIdx.x; i < 8192; i += 256) s_in[i] = in[i];
  __syncthreads();
  if (threadIdx.x < 4) {
    int s = threadIdx.x;
    float v = init;
    for (int t = 0; t < 2048; ++t) {
      outv[t*4+s] = v;
      if (t >= 1) v = 0.99f*v + 0.01f*s_in[t*4+s];
    }
  }
}

// ---------------- K2d: sd[t,s] = mean_b |err - MU[t,s]| ----------------
__global__ void k2d_sd(const float* __restrict__ err, const float* __restrict__ MU, float* __restrict__ sd){
  int i = blockIdx.x*256 + threadIdx.x;       // t*4+s
  float mu = MU[i];
  float sum = 0.f;
  #pragma unroll
  for (int b=0;b<8;++b) sum += fabsf(err[b*8192 + i] - mu);
  sd[i] = sum * 0.125f;
}

// ---------------- K3: g_all[b,t,s,k] for k in {0,1,2} ----------------
__global__ void k3_gall(const float* __restrict__ hg, const float* __restrict__ err,
    const float* __restrict__ MU, const float* __restrict__ SIG,
    const float* __restrict__ gateW1, const float* __restrict__ gateb1,
    const float* __restrict__ gateW2, const float* __restrict__ gateb2,
    const float* __restrict__ semb, float* __restrict__ g_all)
{
  int i = blockIdx.x*256 + threadIdx.x;       // bts*3 + k, total B*T*S*3
  int k = i % 3;
  int bts = i / 3;
  int s = bts & 3;
  int t = (bts >> 2) & 2047;
  float e = err[bts];
  float z = (e - MU[t*4+s]) / fmaxf(SIG[t*4+s], 1e-3f);
  const float* hgp = &hg[(size_t)bts*64];
  float logit = 0.f;
  for (int hh = 0; hh < 64; ++hh) {
    float w1z = gateW1[((size_t)s*521 + 512)*64 + hh];
    float embc = 0.f;
    #pragma unroll
    for (int e2 = 0; e2 < 8; ++e2)
      embc = fmaf(semb[k*8+e2], gateW1[((size_t)s*521 + 513 + e2)*64 + hh], embc);
    float hid = hgp[hh] + z*w1z + embc + gateb1[s*64+hh];
    hid = fmaxf(hid, 0.f);
    logit = fmaf(hid, gateW2[s*64+hh], logit);
  }
  logit += gateb2[s];
  g_all[i] = 1.f/(1.f + expf(-logit));
}

// ---------------- K3b: gm[t,s,k] = mean_b g_all ----------------
__global__ void k3b_gm(const float* __restrict__ g_all, float* __restrict__ gm){
  int i = blockIdx.x*256 + threadIdx.x;       // (t*4+s)*3+k, total 24576
  int k = i % 3; int ts = i / 3;
  float sum = 0.f;
  #pragma unroll
  for (int b=0;b<8;++b) sum += g_all[((size_t)b*8192 + ts)*3 + k];
  gm[i] = sum * 0.125f;
}

// ---------------- K4: state-machine scalar scan ----------------
__global__ void k4_scan(const float* __restrict__ gm, int* __restrict__ states){
  __shared__ float s_gm[6144];    // 512 t x 4 s x 3 k
  float ema = 0.5f; int st = 0;
  for (int c = 0; c < 4; ++c) {
    __syncthreads();
    for (int i = threadIdx.x; i < 6144; i += 256) s_gm[i] = gm[c*6144 + i];
    __syncthreads();
    if (threadIdx.x < 4) {
      int s = threadIdx.x;
      for (int tt = 0; tt < 512; ++tt) {
        int t = c*512 + tt;
        states[t*4+s] = st;
        float g = s_gm[tt*12 + s*3 + st];
        ema = 0.99f*ema + 0.01f*g;
        int ns = st;
        if (st == 0 && ema < 0.1f) ns = 1;
        if (st == 1) ns = (ema < 0.03f) ? 2 : ((ema > 0.25f) ? 0 : 1);
        if (st == 2 && ema > 0.25f) ns = 0;
        st = ns;
      }
    }
  }
}

// ---------------- K5: a[b,t,s] = g_all[...,state] * gain[state] ----------------
__global__ void k5_a(const float* __restrict__ g_all, const int* __restrict__ states, float* __restrict__ a){
  int i = blockIdx.x*256 + threadIdx.x;       // (b*T+t)*4+s
  int ts = i & 8191;
  int st = states[ts];
  float gain = (st == 0) ? 1.f : ((st == 1) ? 0.5f : 0.1f);
  a[i] = g_all[(size_t)i*3 + st] * gain;
}

// ---------------- K6: pass-1 chunk recurrence (q from m=0, P = prod(1-a)) ----------------
__global__ __launch_bounds__(512) void k6_pass1(const float* __restrict__ a, const bf16* __restrict__ wenc,
      float* __restrict__ q, float* __restrict__ Pc){
  int c = blockIdx.x, s = blockIdx.y, b = blockIdx.z;
  int d = threadIdx.x;
  __shared__ float s_a[64];
  if (d < 64) s_a[d] = a[(size_t)(b*2048 + c*64 + d)*4 + s];
  __syncthreads();
  float qv = 0.f, p = 1.f;
  #pragma unroll 4
  for (int i = 0; i < 64; ++i) {
    float av = s_a[i];
    float w = b2f(wenc[((size_t)(b*2048 + c*64 + i)*4 + s)*512 + d]);
    qv = (1.f - av)*qv + av*w;
    p *= (1.f - av);
  }
  q[((size_t)(b*4+s)*32 + c)*512 + d] = qv;
  if (d == 0) Pc[(b*4+s)*32 + c] = p;
}

// ---------------- K7: boundary scan over 32 chunks ----------------
__global__ __launch_bounds__(512) void k7_bound(const float* __restrict__ q, const float* __restrict__ Pc,
      const float* __restrict__ w0, float* __restrict__ m_start){
  int s = blockIdx.x, b = blockIdx.y, d = threadIdx.x;
  float m = w0[s*512 + d];
  for (int c = 0; c < 32; ++c) {
    m_start[((size_t)(b*4+s)*32 + c)*512 + d] = m;
    m = Pc[(b*4+s)*32 + c]*m + q[((size_t)(b*4+s)*32 + c)*512 + d];
  }
}

// ---------------- K8: pass-2 emit outputs ----------------
__global__ __launch_bounds__(512) void k8_pass2(const float* __restrict__ a, const bf16* __restrict__ wenc,
      const float* __restrict__ m_start, float* __restrict__ out){
  int c = blockIdx.x, s = blockIdx.y, b = blockIdx.z;
  int d = threadIdx.x;
  __shared__ float s_a[64];
  if (d < 64) s_a[d] = a[(size_t)(b*2048 + c*64 + d)*4 + s];
  __syncthreads();
  float m = m_start[((size_t)(b*4+s)*32 + c)*512 + d];
  #pragma unroll 4
  for (int i = 0; i < 64; ++i) {
    int t = c*64 + i;
    float av = s_a[i];
    float w = b2f(wenc[((size_t)(b*2048 + t)*4 + s)*512 + d]);
    m = (1.f - av)*m + av*w;
    out[((size_t)b*2048 + t)*2048 + s*512 + d] = m;
  }
}

extern "C" void kernel_launch(void* const* d_in, const int* in_sizes, int n_in,
                              void* d_out, int out_size, void* d_ws, size_t ws_size,
                              hipStream_t stream) {
  (void)in_sizes; (void)n_in; (void)out_size; (void)ws_size;
  const float* h      = (const float*)d_in[0];
  const float* predW  = (const float*)d_in[1];
  const float* predb  = (const float*)d_in[2];
  const float* gateW1 = (const float*)d_in[3];
  const float* gateb1 = (const float*)d_in[4];
  const float* gateW2 = (const float*)d_in[5];
  const float* gateb2 = (const float*)d_in[6];
  const float* writeW = (const float*)d_in[7];
  const float* writeb = (const float*)d_in[8];
  const float* w0     = (const float*)d_in[9];
  const float* semb   = (const float*)d_in[10];
  float* out = (float*)d_out;

  char* ws = (char*)d_ws;
  size_t off = 0;
  auto alloc = [&](size_t bytes) -> char* {
    char* p = ws + off; off += (bytes + 255) / 256 * 256; return p;
  };
  bf16*  wenc   = (bf16*) alloc((size_t)Bb*Tt*Ss*Dd*2);      // 67 MB
  float* hg     = (float*)alloc((size_t)Bb*Tt*Ss*GHh*4);     // 16.8 MB
  float* errsq  = (float*)alloc((size_t)Bb*Tt*Ss*4);
  float* err    = (float*)alloc((size_t)Bb*Tt*Ss*4);
  float* em     = (float*)alloc((size_t)Tt*Ss*4);
  float* MU     = (float*)alloc((size_t)Tt*Ss*4);
  float* sd     = (float*)alloc((size_t)Tt*Ss*4);
  float* SIG    = (float*)alloc((size_t)Tt*Ss*4);
  float* g_all  = (float*)alloc((size_t)Bb*Tt*Ss*3*4);       // 3 MB
  float* gm     = (float*)alloc((size_t)Tt*Ss*3*4);
  int*   states = (int*)  alloc((size_t)Tt*Ss*4);
  float* av     = (float*)alloc((size_t)Bb*Tt*Ss*4);
  float* Pc     = (float*)alloc((size_t)Bb*Ss*NCHUNK*4);
  float* q      = (float*)alloc((size_t)Bb*Ss*NCHUNK*Dd*4);  // 2 MB
  float* mst    = (float*)alloc((size_t)Bb*Ss*NCHUNK*Dd*4);  // 2 MB

  hipMemsetAsync(errsq, 0, (size_t)Bb*Tt*Ss*4, stream);

  dim3 g1(68, 256);
  k1_gemm<<<g1, 256, 0, stream>>>(h, predW, predb, gateW1, writeW, writeb, wenc, hg, errsq);
  k2a_err<<<(Bb*Tt*Ss)/256, 256, 0, stream>>>(errsq, err);
  k2b_em<<<(Tt*Ss)/256, 256, 0, stream>>>(err, em);
  k2c_scan<<<1, 256, 0, stream>>>(em, MU, 0.f);
  k2d_sd<<<(Tt*Ss)/256, 256, 0, stream>>>(err, MU, sd);
  k2c_scan<<<1, 256, 0, stream>>>(sd, SIG, 1.f);
  k3_gall<<<(Bb*Tt*Ss*3)/256, 256, 0, stream>>>(hg, err, MU, SIG, gateW1, gateb1, gateW2, gateb2, semb, g_all);
  k3b_gm<<<(Tt*Ss*3)/256, 256, 0, stream>>>(g_all, gm);
  k4_scan<<<1, 256, 0, stream>>>(gm, states);
  k5_a<<<(Bb*Tt*Ss)/256, 256, 0, stream>>>(g_all, states, av);
  dim3 g6(NCHUNK, Ss, Bb);
  k6_pass1<<<g6, 512, 0, stream>>>(av, wenc, q, Pc);
  dim3 g7(Ss, Bb);
  k7_bound<<<g7, 512, 0, stream>>>(q, Pc, w0, mst);
  k8_pass2<<<g6, 512, 0, stream>>>(av, wenc, mst, out);
}

// Round 3
// 665.357 us; speedup vs baseline: 2.3669x; 2.3669x over previous
//
#include <hip/hip_runtime.h>
#include <hip/hip_bf16.h>

#define Bb 8
#define Tt 2048
#define Dd 512
#define Ss 4
#define GHh 64
#define NCHUNK 32

typedef __hip_bfloat16 bf16;
typedef short bf16x8 __attribute__((ext_vector_type(8)));
typedef float f32x4 __attribute__((ext_vector_type(4)));
__device__ __forceinline__ float b2f(bf16 x){ return __bfloat162float(x); }

#define GLOAD_LDS16(g, l) \
  __builtin_amdgcn_global_load_lds((const __attribute__((address_space(1))) unsigned int*)(const void*)(g), \
                                   (__attribute__((address_space(3))) unsigned int*)(l), 16, 0, 0)

// ---------------- K0a: h f32 -> bf16 ----------------
__global__ __launch_bounds__(256) void k0a_cvt(const float* __restrict__ h, bf16* __restrict__ hb){
  int i = (blockIdx.x*256 + threadIdx.x)*4;
  float4 v = *reinterpret_cast<const float4*>(&h[i]);
  hb[i+0] = __float2bfloat16(v.x);
  hb[i+1] = __float2bfloat16(v.y);
  hb[i+2] = __float2bfloat16(v.z);
  hb[i+3] = __float2bfloat16(v.w);
}

// ---------------- K0b: pack+transpose weights -> Wt[4352][512] bf16 ----------------
__global__ __launch_bounds__(256) void k0b_pack(const float* __restrict__ predW,
    const float* __restrict__ writeW, const float* __restrict__ gateW1, bf16* __restrict__ Wt){
  __shared__ float tile[32][33];
  int k0 = blockIdx.x*32, n0 = blockIdx.y*32;
  int tx = threadIdx.x & 31, ty = threadIdx.x >> 5;   // 32 x 8
  #pragma unroll
  for (int p = 0; p < 4; ++p) {
    int kk = ty + p*8;
    int n = n0 + tx, k = k0 + kk;
    float v;
    if (n < 2048)      { int s=n>>9, o=n&511;              v = predW[((size_t)s*512+k)*512+o]; }
    else if (n < 4096) { int n2=n-2048; int s=n2>>9,o=n2&511; v = writeW[((size_t)s*512+k)*512+o]; }
    else               { int n2=n-4096; int s=n2>>6,hh=n2&63; v = gateW1[((size_t)s*521+k)*64+hh]; }
    tile[kk][tx] = v;
  }
  __syncthreads();
  #pragma unroll
  for (int p = 0; p < 4; ++p) {
    int nn = ty + p*8;
    Wt[(size_t)(n0+nn)*512 + k0 + tx] = __float2bfloat16(tile[tx][nn]);
  }
}

// ---------------- K1: MFMA GEMM  M=16384, K=512, N=4352 (B^T layout) ----------------
// N sections: [0,2048) pred -> err^2 partials (atomic)
//             [2048,4096) write-enc -> wenc (bf16)
//             [4096,4352) gate h-contrib -> hg (f32)
__global__ __launch_bounds__(256) void k1_mfma(
    const bf16* __restrict__ hb, const bf16* __restrict__ Wt,
    const float* __restrict__ h, const float* __restrict__ predb, const float* __restrict__ writeb,
    bf16* __restrict__ wenc, float* __restrict__ hg, float* __restrict__ errsq)
{
  __shared__ bf16 As[128*32];
  __shared__ bf16 Bs[128*32];
  const int tid = threadIdx.x;
  const int w = tid >> 6, lane = tid & 63;
  const int n0 = blockIdx.x * 128;     // 0..33
  const int row0 = blockIdx.y * 128;   // 0..127
  const int wm = w & 1, wn = w >> 1;   // 2x2 waves of 64x64
  const int mrow = lane & 15, kq = lane >> 4;

  f32x4 acc[4][4];
  #pragma unroll
  for (int i=0;i<4;++i)
    #pragma unroll
    for (int j=0;j<4;++j) acc[i][j] = (f32x4){0.f,0.f,0.f,0.f};

  // staging: wave w covers tile rows [w*32, w*32+32); each inst = 16 rows
  const bf16* ga = hb + (size_t)(row0 + w*32 + (lane>>2))*512 + (lane&3)*8;
  const bf16* gb = Wt + (size_t)(n0  + w*32 + (lane>>2))*512 + (lane&3)*8;
  bf16* lA = &As[(w*32)*32];
  bf16* lB = &Bs[(w*32)*32];

  for (int k0 = 0; k0 < 512; k0 += 32) {
    GLOAD_LDS16(ga,           lA);
    GLOAD_LDS16(ga + 16*512,  lA + 16*32);
    GLOAD_LDS16(gb,           lB);
    GLOAD_LDS16(gb + 16*512,  lB + 16*32);
    ga += 32; gb += 32;
    __syncthreads();   // drains vmcnt(0) -> LDS ready
    bf16x8 af[4], bfr[4];
    #pragma unroll
    for (int mi=0;mi<4;++mi)
      af[mi] = *reinterpret_cast<const bf16x8*>(&As[(wm*64 + mi*16 + mrow)*32 + kq*8]);
    #pragma unroll
    for (int ni=0;ni<4;++ni)
      bfr[ni] = *reinterpret_cast<const bf16x8*>(&Bs[(wn*64 + ni*16 + mrow)*32 + kq*8]);
    #pragma unroll
    for (int mi=0;mi<4;++mi)
      #pragma unroll
      for (int ni=0;ni<4;++ni)
        acc[mi][ni] = __builtin_amdgcn_mfma_f32_16x16x32_bf16(af[mi], bfr[ni], acc[mi][ni], 0, 0, 0);
    __syncthreads();   // before next overwrite
  }

  // epilogue: D element (mi,ni,reg) -> row = row0+wm*64+mi*16+kq*4+reg, col = n0+wn*64+ni*16+mrow
  if (n0 < 2048) {
    const int s = n0 >> 9;
    #pragma unroll
    for (int mi=0;mi<4;++mi) {
      #pragma unroll
      for (int reg=0;reg<4;++reg) {
        int r = row0 + wm*64 + mi*16 + kq*4 + reg;
        float sum = 0.f;
        if ((r & 2047) != 2047) {
          #pragma unroll
          for (int ni=0;ni<4;++ni) {
            int o = (n0 & 511) + wn*64 + ni*16 + mrow;
            float P = acc[mi][ni][reg] + predb[s*512 + o];
            float d = P - h[(size_t)(r+1)*512 + o];
            sum = fmaf(d, d, sum);
          }
        }
        #pragma unroll
        for (int off=1; off<16; off<<=1) sum += __shfl_xor(sum, off);
        if (mrow == 0 && (r & 2047) != 2047)
          atomicAdd(&errsq[(size_t)(r+1)*4 + s], sum);
      }
    }
  } else if (n0 < 4096) {
    #pragma unroll
    for (int mi=0;mi<4;++mi)
      #pragma unroll
      for (int ni=0;ni<4;++ni) {
        int n2 = n0 - 2048 + wn*64 + ni*16 + mrow;
        int s = n2 >> 9, o = n2 & 511;
        float wb = writeb[s*512 + o];
        #pragma unroll
        for (int reg=0;reg<4;++reg) {
          int r = row0 + wm*64 + mi*16 + kq*4 + reg;
          wenc[((size_t)r*4 + s)*512 + o] = __float2bfloat16(acc[mi][ni][reg] + wb);
        }
      }
  } else {
    #pragma unroll
    for (int mi=0;mi<4;++mi)
      #pragma unroll
      for (int ni=0;ni<4;++ni) {
        int n2 = n0 - 4096 + wn*64 + ni*16 + mrow;
        int s = n2 >> 6, hh = n2 & 63;
        #pragma unroll
        for (int reg=0;reg<4;++reg) {
          int r = row0 + wm*64 + mi*16 + kq*4 + reg;
          hg[((size_t)r*4 + s)*64 + hh] = acc[mi][ni][reg];
        }
      }
  }
}

// ---------------- K2a: err = sqrt(errsq + 1e-8), 0 at t==0 ----------------
__global__ void k2a_err(const float* __restrict__ errsq, float* __restrict__ err){
  int i = blockIdx.x*256 + threadIdx.x;
  int t = (i >> 2) & 2047;
  err[i] = (t > 0) ? sqrtf(errsq[i] + 1e-8f) : 0.f;
}

// ---------------- K2b: em[t,s] = mean_b err ----------------
__global__ void k2b_em(const float* __restrict__ err, float* __restrict__ em){
  int i = blockIdx.x*256 + threadIdx.x;
  float sum = 0.f;
  #pragma unroll
  for (int b=0;b<8;++b) sum += err[b*8192 + i];
  em[i] = sum * 0.125f;
}

// ---------------- K2c: scalar EMA scan ----------------
__global__ void k2c_scan(const float* __restrict__ in, float* __restrict__ outv, float init){
  __shared__ float s_in[8192];
  for (int i = threadIdx.x; i < 8192; i += 256) s_in[i] = in[i];
  __syncthreads();
  if (threadIdx.x < 4) {
    int s = threadIdx.x;
    float v = init;
    for (int t = 0; t < 2048; ++t) {
      outv[t*4+s] = v;
      if (t >= 1) v = 0.99f*v + 0.01f*s_in[t*4+s];
    }
  }
}

// ---------------- K2d: sd[t,s] = mean_b |err - MU| ----------------
__global__ void k2d_sd(const float* __restrict__ err, const float* __restrict__ MU, float* __restrict__ sd){
  int i = blockIdx.x*256 + threadIdx.x;
  float mu = MU[i];
  float sum = 0.f;
  #pragma unroll
  for (int b=0;b<8;++b) sum += fabsf(err[b*8192 + i] - mu);
  sd[i] = sum * 0.125f;
}

// ---------------- K2e: base1[s][k][hh] = gateb1 + semb[k] . gateW1[513:521] ----------------
__global__ void k2e_base(const float* __restrict__ gateW1, const float* __restrict__ semb,
                         const float* __restrict__ gateb1, float* __restrict__ base1){
  int i = blockIdx.x*256 + threadIdx.x;   // (s*3+k)*64+hh, total 768
  if (i < 768) {
    int hh = i & 63, k = (i >> 6) % 3, s = i / 192;
    float acc = gateb1[s*64 + hh];
    #pragma unroll
    for (int e = 0; e < 8; ++e)
      acc = fmaf(semb[k*8+e], gateW1[((size_t)s*521 + 513 + e)*64 + hh], acc);
    base1[i] = acc;
  }
}

// ---------------- K3: g_all[b,t,s,k] ----------------
__global__ void k3_gall(const float* __restrict__ hg, const float* __restrict__ err,
    const float* __restrict__ MU, const float* __restrict__ SIG,
    const float* __restrict__ gateW1, const float* __restrict__ base1,
    const float* __restrict__ gateW2, const float* __restrict__ gateb2,
    float* __restrict__ g_all)
{
  int i = blockIdx.x*256 + threadIdx.x;   // bts*3 + k
  int k = i % 3;
  int bts = i / 3;
  int s = bts & 3;
  int t = (bts >> 2) & 2047;
  float e = err[bts];
  float z = (e - MU[t*4+s]) / fmaxf(SIG[t*4+s], 1e-3f);
  const float* hgp = &hg[(size_t)bts*64];
  const float* b1p = &base1[(s*3 + k)*64];
  const float* w1zp = &gateW1[((size_t)s*521 + 512)*64];
  const float* w2p = &gateW2[s*64];
  float logit = 0.f;
  for (int hh = 0; hh < 64; ++hh) {
    float hid = hgp[hh] + z*w1zp[hh] + b1p[hh];
    hid = fmaxf(hid, 0.f);
    logit = fmaf(hid, w2p[hh], logit);
  }
  logit += gateb2[s];
  g_all[i] = 1.f/(1.f + expf(-logit));
}

// ---------------- K3b: gm[t,s,k] = mean_b g_all ----------------
__global__ void k3b_gm(const float* __restrict__ g_all, float* __restrict__ gm){
  int i = blockIdx.x*256 + threadIdx.x;
  float sum = 0.f;
  #pragma unroll
  for (int b=0;b<8;++b) sum += g_all[((size_t)b*8192 + i/3)*3 + (i%3)];
  gm[i] = sum * 0.125f;
}

// ---------------- K4: state-machine scalar scan ----------------
__global__ void k4_scan(const float* __restrict__ gm, int* __restrict__ states){
  __shared__ float s_gm[6144];
  float ema = 0.5f; int st = 0;
  for (int c = 0; c < 4; ++c) {
    __syncthreads();
    for (int i = threadIdx.x; i < 6144; i += 256) s_gm[i] = gm[c*6144 + i];
    __syncthreads();
    if (threadIdx.x < 4) {
      int s = threadIdx.x;
      for (int tt = 0; tt < 512; ++tt) {
        int t = c*512 + tt;
        states[t*4+s] = st;
        float g = s_gm[tt*12 + s*3 + st];
        ema = 0.99f*ema + 0.01f*g;
        int ns = st;
        if (st == 0 && ema < 0.1f) ns = 1;
        if (st == 1) ns = (ema < 0.03f) ? 2 : ((ema > 0.25f) ? 0 : 1);
        if (st == 2 && ema > 0.25f) ns = 0;
        st = ns;
      }
    }
  }
}

// ---------------- K5: a[b,t,s] = g_all[...,state] * gain[state] ----------------
__global__ void k5_a(const float* __restrict__ g_all, const int* __restrict__ states, float* __restrict__ a){
  int i = blockIdx.x*256 + threadIdx.x;
  int ts = i & 8191;
  int st = states[ts];
  float gain = (st == 0) ? 1.f : ((st == 1) ? 0.5f : 0.1f);
  a[i] = g_all[(size_t)i*3 + st] * gain;
}

// ---------------- K6: pass-1 chunk recurrence ----------------
__global__ __launch_bounds__(512) void k6_pass1(const float* __restrict__ a, const bf16* __restrict__ wenc,
      float* __restrict__ q, float* __restrict__ Pc){
  int c = blockIdx.x, s = blockIdx.y, b = blockIdx.z;
  int d = threadIdx.x;
  __shared__ float s_a[64];
  if (d < 64) s_a[d] = a[(size_t)(b*2048 + c*64 + d)*4 + s];
  __syncthreads();
  float qv = 0.f, p = 1.f;
  #pragma unroll 4
  for (int i = 0; i < 64; ++i) {
    float av = s_a[i];
    float w = b2f(wenc[((size_t)(b*2048 + c*64 + i)*4 + s)*512 + d]);
    qv = (1.f - av)*qv + av*w;
    p *= (1.f - av);
  }
  q[((size_t)(b*4+s)*32 + c)*512 + d] = qv;
  if (d == 0) Pc[(b*4+s)*32 + c] = p;
}

// ---------------- K7: boundary scan ----------------
__global__ __launch_bounds__(512) void k7_bound(const float* __restrict__ q, const float* __restrict__ Pc,
      const float* __restrict__ w0, float* __restrict__ m_start){
  int s = blockIdx.x, b = blockIdx.y, d = threadIdx.x;
  float m = w0[s*512 + d];
  for (int c = 0; c < 32; ++c) {
    m_start[((size_t)(b*4+s)*32 + c)*512 + d] = m;
    m = Pc[(b*4+s)*32 + c]*m + q[((size_t)(b*4+s)*32 + c)*512 + d];
  }
}

// ---------------- K8: pass-2 emit ----------------
__global__ __launch_bounds__(512) void k8_pass2(const float* __restrict__ a, const bf16* __restrict__ wenc,
      const float* __restrict__ m_start, float* __restrict__ out){
  int c = blockIdx.x, s = blockIdx.y, b = blockIdx.z;
  int d = threadIdx.x;
  __shared__ float s_a[64];
  if (d < 64) s_a[d] = a[(size_t)(b*2048 + c*64 + d)*4 + s];
  __syncthreads();
  float m = m_start[((size_t)(b*4+s)*32 + c)*512 + d];
  #pragma unroll 4
  for (int i = 0; i < 64; ++i) {
    int t = c*64 + i;
    float av = s_a[i];
    float w = b2f(wenc[((size_t)(b*2048 + t)*4 + s)*512 + d]);
    m = (1.f - av)*m + av*w;
    out[((size_t)b*2048 + t)*2048 + s*512 + d] = m;
  }
}

extern "C" void kernel_launch(void* const* d_in, const int* in_sizes, int n_in,
                              void* d_out, int out_size, void* d_ws, size_t ws_size,
                              hipStream_t stream) {
  (void)in_sizes; (void)n_in; (void)out_size; (void)ws_size;
  const float* h      = (const float*)d_in[0];
  const float* predW  = (const float*)d_in[1];
  const float* predb  = (const float*)d_in[2];
  const float* gateW1 = (const float*)d_in[3];
  const float* gateb1 = (const float*)d_in[4];
  const float* gateW2 = (const float*)d_in[5];
  const float* gateb2 = (const float*)d_in[6];
  const float* writeW = (const float*)d_in[7];
  const float* writeb = (const float*)d_in[8];
  const float* w0     = (const float*)d_in[9];
  const float* semb   = (const float*)d_in[10];
  float* out = (float*)d_out;

  char* ws = (char*)d_ws;
  size_t off = 0;
  auto alloc = [&](size_t bytes) -> char* {
    char* p = ws + off; off += (bytes + 255) / 256 * 256; return p;
  };
  bf16*  wenc   = (bf16*) alloc((size_t)Bb*Tt*Ss*Dd*2);      // 67 MB
  float* hg     = (float*)alloc((size_t)Bb*Tt*Ss*GHh*4);     // 16.8 MB
  bf16*  hb     = (bf16*) alloc((size_t)Bb*Tt*Dd*2);         // 16.8 MB
  bf16*  Wt     = (bf16*) alloc((size_t)4352*512*2);         // 4.5 MB
  float* errsq  = (float*)alloc((size_t)Bb*Tt*Ss*4);
  float* err    = (float*)alloc((size_t)Bb*Tt*Ss*4);
  float* em     = (float*)alloc((size_t)Tt*Ss*4);
  float* MU     = (float*)alloc((size_t)Tt*Ss*4);
  float* sd     = (float*)alloc((size_t)Tt*Ss*4);
  float* SIG    = (float*)alloc((size_t)Tt*Ss*4);
  float* base1  = (float*)alloc((size_t)Ss*3*GHh*4);
  float* g_all  = (float*)alloc((size_t)Bb*Tt*Ss*3*4);       // 3 MB
  float* gm     = (float*)alloc((size_t)Tt*Ss*3*4);
  int*   states = (int*)  alloc((size_t)Tt*Ss*4);
  float* av     = (float*)alloc((size_t)Bb*Tt*Ss*4);
  float* Pc     = (float*)alloc((size_t)Bb*Ss*NCHUNK*4);
  float* q      = (float*)alloc((size_t)Bb*Ss*NCHUNK*Dd*4);  // 2 MB
  float* mst    = (float*)alloc((size_t)Bb*Ss*NCHUNK*Dd*4);  // 2 MB

  hipMemsetAsync(errsq, 0, (size_t)Bb*Tt*Ss*4, stream);

  k0a_cvt<<<(Bb*Tt*Dd)/(256*4), 256, 0, stream>>>(h, hb);
  dim3 g0b(16, 136);
  k0b_pack<<<g0b, 256, 0, stream>>>(predW, writeW, gateW1, Wt);
  dim3 g1(34, 128);
  k1_mfma<<<g1, 256, 0, stream>>>(hb, Wt, h, predb, writeb, wenc, hg, errsq);
  k2a_err<<<(Bb*Tt*Ss)/256, 256, 0, stream>>>(errsq, err);
  k2b_em<<<(Tt*Ss)/256, 256, 0, stream>>>(err, em);
  k2c_scan<<<1, 256, 0, stream>>>(em, MU, 0.f);
  k2d_sd<<<(Tt*Ss)/256, 256, 0, stream>>>(err, MU, sd);
  k2c_scan<<<1, 256, 0, stream>>>(sd, SIG, 1.f);
  k2e_base<<<3, 256, 0, stream>>>(gateW1, semb, gateb1, base1);
  k3_gall<<<(Bb*Tt*Ss*3)/256, 256, 0, stream>>>(hg, err, MU, SIG, gateW1, base1, gateW2, gateb2, g_all);
  k3b_gm<<<(Tt*Ss*3)/256, 256, 0, stream>>>(g_all, gm);
  k4_scan<<<1, 256, 0, stream>>>(gm, states);
  k5_a<<<(Bb*Tt*Ss)/256, 256, 0, stream>>>(g_all, states, av);
  dim3 g6(NCHUNK, Ss, Bb);
  k6_pass1<<<g6, 512, 0, stream>>>(av, wenc, q, Pc);
  dim3 g7(Ss, Bb);
  k7_bound<<<g7, 512, 0, stream>>>(q, Pc, w0, mst);
  k8_pass2<<<g6, 512, 0, stream>>>(av, wenc, mst, out);
}